// Round 3
// baseline (88.454 us; speedup 1.0000x reference)
//
#include <hip/hip_runtime.h>
#include <hip/hip_bf16.h>
#include <math.h>

// Problem constants
#define BB 2
#define HH 64
#define WW 64
#define DIMC 128
#define NH 4
#define HD 32
#define KS 7
#define DIL 2
#define NPIX (BB * HH * WW)         // 8192 rows
#define SCALE 0.17677669529663687f  // 32^-0.5

// ---------------------------------------------------------------------------
// GEMM body: Y[r,c] = (sum_k X[r,k] * W[k,c] + b[c]) * scale
// Block = 8 rows x 128 cols, 256 threads. Thread = 2 cols x 2 rows (acc 2x2).
// X float4 reads are wave-uniform LDS broadcasts; 8 FMAs per LDS read.
// ---------------------------------------------------------------------------
__device__ __forceinline__ void gemm_body(
    const float* __restrict__ X, const float* __restrict__ W,
    const float* __restrict__ bias, float* __restrict__ Y, float scale,
    int block)
{
    __shared__ float4 Xs[8 * 32];  // 8 rows x 128 floats

    const int t = threadIdx.x;
    const float4* Xg = (const float4*)(X + (size_t)block * 8 * 128);
    Xs[t] = Xg[t];
    __syncthreads();

    const int cg = t & 63;   // column pair: cols {2cg, 2cg+1}
    const int rg = t >> 6;   // 0..3 -> rows {2rg, 2rg+1}
    const float2* W2 = (const float2*)W;

    float2 acc[2];
    const float2 bc = *(const float2*)(bias + 2 * cg);
    acc[0] = bc;
    acc[1] = bc;

#pragma unroll 8
    for (int k4 = 0; k4 < 32; ++k4) {
        const float2 w0 = W2[(4 * k4 + 0) * 64 + cg];
        const float2 w1 = W2[(4 * k4 + 1) * 64 + cg];
        const float2 w2 = W2[(4 * k4 + 2) * 64 + cg];
        const float2 w3 = W2[(4 * k4 + 3) * 64 + cg];
#pragma unroll
        for (int r = 0; r < 2; ++r) {
            const float4 x = Xs[(2 * rg + r) * 32 + k4];
            acc[r].x = fmaf(x.x, w0.x, acc[r].x);
            acc[r].y = fmaf(x.x, w0.y, acc[r].y);
            acc[r].x = fmaf(x.y, w1.x, acc[r].x);
            acc[r].y = fmaf(x.y, w1.y, acc[r].y);
            acc[r].x = fmaf(x.z, w2.x, acc[r].x);
            acc[r].y = fmaf(x.z, w2.y, acc[r].y);
            acc[r].x = fmaf(x.w, w3.x, acc[r].x);
            acc[r].y = fmaf(x.w, w3.y, acc[r].y);
        }
    }

    float2* Y2 = (float2*)(Y + (size_t)block * 8 * 128);
#pragma unroll
    for (int r = 0; r < 2; ++r) {
        float2 out;
        out.x = acc[r].x * scale;
        out.y = acc[r].y * scale;
        Y2[(2 * rg + r) * 64 + cg] = out;
    }
}

// Fused Q/K/V projection: grid (1024, 3)
__global__ __launch_bounds__(256) void qkv_gemm(
    const float* __restrict__ q, const float* __restrict__ k,
    const float* __restrict__ v,
    const float* __restrict__ Wq, const float* __restrict__ Wk,
    const float* __restrict__ Wv,
    const float* __restrict__ bq, const float* __restrict__ bk,
    const float* __restrict__ bv,
    float* __restrict__ qh, float* __restrict__ kh, float* __restrict__ vh)
{
    const int z = blockIdx.y;
    const float* X    = (z == 0) ? q  : (z == 1) ? k  : v;
    const float* W    = (z == 0) ? Wq : (z == 1) ? Wk : Wv;
    const float* bias = (z == 0) ? bq : (z == 1) ? bk : bv;
    float*       Y    = (z == 0) ? qh : (z == 1) ? kh : vh;
    const float scale = (z == 0) ? SCALE : 1.0f;
    gemm_body(X, W, bias, Y, scale, blockIdx.x);
}

__global__ __launch_bounds__(256) void out_gemm(
    const float* __restrict__ X, const float* __restrict__ W,
    const float* __restrict__ bias, float* __restrict__ Y)
{
    gemm_body(X, W, bias, Y, 1.0f, blockIdx.x);
}

// ---------------------------------------------------------------------------
// NATTEN edge-index helper (L=64, K=7, dil=2, ns=3).
// ---------------------------------------------------------------------------
__device__ __forceinline__ void natten_idx(int i, int& s, int& p)
{
    if (i < 6) {                 // i - ns*dil < 0
        s = i & 1;
        p = 6 - (i >> 1);
    } else if (i >= 58) {        // i + ns*dil >= L  (L%dil==0 -> b=0 path)
        s = 50 + (i & 1);        // a + i%dil - K*dil
        p = (63 - i) >> 1;
    } else {
        s = i - 6;
        p = 3;
    }
}

// ---------------------------------------------------------------------------
// Neighborhood attention, two-pass register version.
// 8 lanes per (b,i,j,head); each lane owns 4 channels.
// Pass 1: 49 independent partial dots -> 147 independent shuffles -> bias,
// tree max, independent exps. Pass 2: PV accumulation (V re-read from L2).
// All score indices compile-time (full unroll) to stay in registers.
// ---------------------------------------------------------------------------
__global__ __launch_bounds__(256) void natten_kernel(
    const float* __restrict__ qh, const float* __restrict__ kh,
    const float* __restrict__ vh, const float* __restrict__ rpb,
    float* __restrict__ att)
{
    const int glob = blockIdx.x * 256 + threadIdx.x;  // 0..262143
    const int q4 = glob & 7;          // channel quarter (4 floats)
    const int n  = (glob >> 3) & 3;   // head
    const int j  = (glob >> 5) & 63;
    const int i  = (glob >> 11) & 63;
    const int b  = glob >> 17;

    int si, pi0, sj, pj0;
    natten_idx(i, si, pi0);
    natten_idx(j, sj, pj0);

    const int coff = n * 32 + q4 * 4;
    const size_t pix = (size_t)(b * 4096 + i * 64 + j);
    const float4 qv = *(const float4*)(qh + pix * 128 + coff);

    const float* rp = rpb + n * 169;  // [13][13]

    float sc[49];

    // ---- Pass 1: partial dot products (independent loads, no chain) ----
#pragma unroll
    for (int ki = 0; ki < 7; ++ki) {
        const int iy = si + 2 * ki;
        const size_t rowbase = ((size_t)(b * 4096 + iy * 64)) * 128 + coff;
#pragma unroll
        for (int kj = 0; kj < 7; ++kj) {
            const int ix = sj + 2 * kj;
            const float4 kv = *(const float4*)(kh + rowbase + (size_t)ix * 128);
            sc[ki * 7 + kj] =
                fmaf(qv.x, kv.x, fmaf(qv.y, kv.y, fmaf(qv.z, kv.z, qv.w * kv.w)));
        }
    }

    // ---- Cross-lane reduce: 3 rounds of independent shuffles ----
#pragma unroll
    for (int t = 0; t < 49; ++t) sc[t] += __shfl_xor(sc[t], 1);
#pragma unroll
    for (int t = 0; t < 49; ++t) sc[t] += __shfl_xor(sc[t], 2);
#pragma unroll
    for (int t = 0; t < 49; ++t) sc[t] += __shfl_xor(sc[t], 4);

    // ---- Bias + max (tree-ish via 4 partial maxes) ----
    float m0 = -1e30f, m1 = -1e30f, m2 = -1e30f, m3 = -1e30f;
#pragma unroll
    for (int t = 0; t < 49; ++t) {
        const int ki = t / 7, kj = t % 7;
        sc[t] += rp[(pi0 + ki) * 13 + (pj0 + kj)];
        if ((t & 3) == 0)      m0 = fmaxf(m0, sc[t]);
        else if ((t & 3) == 1) m1 = fmaxf(m1, sc[t]);
        else if ((t & 3) == 2) m2 = fmaxf(m2, sc[t]);
        else                   m3 = fmaxf(m3, sc[t]);
    }
    const float m = fmaxf(fmaxf(m0, m1), fmaxf(m2, m3));

    // ---- Exponentials (independent) + 4-way partial sums ----
    float l0 = 0.f, l1 = 0.f, l2 = 0.f, l3 = 0.f;
#pragma unroll
    for (int t = 0; t < 49; ++t) {
        const float p = __expf(sc[t] - m);
        sc[t] = p;
        if ((t & 3) == 0)      l0 += p;
        else if ((t & 3) == 1) l1 += p;
        else if ((t & 3) == 2) l2 += p;
        else                   l3 += p;
    }
    const float inv = 1.0f / ((l0 + l1) + (l2 + l3));

    // ---- Pass 2: PV accumulation (2 chains per channel) ----
    float4 oa = make_float4(0.f, 0.f, 0.f, 0.f);
    float4 ob = make_float4(0.f, 0.f, 0.f, 0.f);
#pragma unroll
    for (int ki = 0; ki < 7; ++ki) {
        const int iy = si + 2 * ki;
        const size_t rowbase = ((size_t)(b * 4096 + iy * 64)) * 128 + coff;
#pragma unroll
        for (int kj = 0; kj < 7; ++kj) {
            const int ix = sj + 2 * kj;
            const float4 vv = *(const float4*)(vh + rowbase + (size_t)ix * 128);
            const float p = sc[ki * 7 + kj];
            if (((ki * 7 + kj) & 1) == 0) {
                oa.x = fmaf(p, vv.x, oa.x);
                oa.y = fmaf(p, vv.y, oa.y);
                oa.z = fmaf(p, vv.z, oa.z);
                oa.w = fmaf(p, vv.w, oa.w);
            } else {
                ob.x = fmaf(p, vv.x, ob.x);
                ob.y = fmaf(p, vv.y, ob.y);
                ob.z = fmaf(p, vv.z, ob.z);
                ob.w = fmaf(p, vv.w, ob.w);
            }
        }
    }

    float4* op = (float4*)(att + pix * 128 + coff);
    *op = make_float4((oa.x + ob.x) * inv, (oa.y + ob.y) * inv,
                      (oa.z + ob.z) * inv, (oa.w + ob.w) * inv);
}

// ---------------------------------------------------------------------------
extern "C" void kernel_launch(void* const* d_in, const int* in_sizes, int n_in,
                              void* d_out, int out_size, void* d_ws, size_t ws_size,
                              hipStream_t stream)
{
    const float* q   = (const float*)d_in[0];
    const float* k   = (const float*)d_in[1];
    const float* v   = (const float*)d_in[2];
    const float* Wq  = (const float*)d_in[3];
    const float* bq  = (const float*)d_in[4];
    const float* Wk  = (const float*)d_in[5];
    const float* bk  = (const float*)d_in[6];
    const float* Wv  = (const float*)d_in[7];
    const float* bv  = (const float*)d_in[8];
    const float* rpb = (const float*)d_in[9];
    const float* Wo  = (const float*)d_in[10];
    const float* bo  = (const float*)d_in[11];

    float* ws  = (float*)d_ws;
    float* qh  = ws;                       // 8192*128
    float* kh  = ws + (size_t)NPIX * 128;
    float* vh  = ws + (size_t)NPIX * 128 * 2;
    float* att = ws + (size_t)NPIX * 128 * 3;
    float* out = (float*)d_out;

    hipLaunchKernelGGL(qkv_gemm, dim3(1024, 3), dim3(256), 0, stream,
                       q, k, v, Wq, Wk, Wv, bq, bk, bv, qh, kh, vh);

    hipLaunchKernelGGL(natten_kernel, dim3(1024), dim3(256), 0, stream,
                       qh, kh, vh, rpb, att);

    hipLaunchKernelGGL(out_gemm, dim3(1024), dim3(256), 0, stream,
                       att, Wo, bo, out);
}

// Round 4
// 54.041 us; speedup vs baseline: 1.6368x; 1.6368x over previous
//
#include <hip/hip_runtime.h>
#include <hip/hip_bf16.h>
#include <math.h>

// Problem constants
#define BB 2
#define HH 64
#define WW 64
#define DIMC 128
#define NH 4
#define HD 32
#define KS 7
#define DIL 2
#define NPIX (BB * HH * WW)         // 8192 rows
#define SCALE 0.17677669529663687f  // 32^-0.5

typedef short bf16x8 __attribute__((ext_vector_type(8)));
typedef float f32x4  __attribute__((ext_vector_type(4)));

__device__ __forceinline__ short bf16r(float f) {
    union { float f; unsigned u; } x; x.f = f;
    unsigned r = x.u + 0x7FFF + ((x.u >> 16) & 1);  // RNE
    return (short)(r >> 16);
}

// ---------------------------------------------------------------------------
// prep_w: convert W (f32 [128][128], row=k, col=n) -> Wt bf16 [n][k] (transposed)
// One block per matrix. LDS transpose with +2-short pad (bank-conflict-free).
// ---------------------------------------------------------------------------
__global__ __launch_bounds__(256) void prep_w(
    const float* __restrict__ Wq, const float* __restrict__ Wk,
    const float* __restrict__ Wv, short* __restrict__ Wt)
{
    const int z = blockIdx.x;
    const float* W = (z == 0) ? Wq : (z == 1) ? Wk : Wv;
    __shared__ short T[128][130];
    const int t = threadIdx.x;
#pragma unroll 4
    for (int e = 0; e < 64; ++e) {
        const int idx = e * 256 + t;       // coalesced read
        const int k = idx >> 7, c = idx & 127;
        T[c][k] = bf16r(W[idx]);
    }
    __syncthreads();
    short* out = Wt + z * 16384;
#pragma unroll 4
    for (int e = 0; e < 64; ++e) {
        const int idx = e * 256 + t;       // coalesced write
        const int r = idx >> 7, c = idx & 127;
        out[idx] = T[r][c];
    }
}

// ---------------------------------------------------------------------------
// qkv_mfma: Y = (X @ W + b) * scale via v_mfma_f32_16x16x32_bf16.
// Block = 32 rows x 128 cols, 4 waves; wave = 16 rows x 64 cols (4 n-tiles).
// A-frags: direct f32 loads + bf16 pack (each element read once per col-half).
// B-frags: b128 loads from pre-transposed bf16 Wt[col][k] (L1/L2 resident).
// Fragment layouts: A/B lane holds 8 contiguous k at k0=(lane>>4)*8 (m92/m93);
// C/D: col=lane&15, row=(lane>>4)*4+reg (m89-verified).
// ---------------------------------------------------------------------------
__global__ __launch_bounds__(256) void qkv_mfma(
    const float* __restrict__ q, const float* __restrict__ k,
    const float* __restrict__ v, const short* __restrict__ Wt,
    const float* __restrict__ bq, const float* __restrict__ bk,
    const float* __restrict__ bv,
    float* __restrict__ qh, float* __restrict__ kh, float* __restrict__ vh)
{
    const int z = blockIdx.y;
    const float* X    = (z == 0) ? q  : (z == 1) ? k  : v;
    const float* bias = (z == 0) ? bq : (z == 1) ? bk : bv;
    float*       Y    = (z == 0) ? qh : (z == 1) ? kh : vh;
    const float scale = (z == 0) ? SCALE : 1.0f;
    const short* Wz   = Wt + z * 16384;

    const int t    = threadIdx.x;
    const int wv   = t >> 6;
    const int lane = t & 63;
    const int lr   = lane & 15;
    const int lg   = lane >> 4;
    const int row0 = blockIdx.x * 32 + (wv & 1) * 16;
    const int col0 = (wv >> 1) * 64;

    // A fragments: 16 rows x 128 k, 8 contiguous k per lane per kk-step
    const float* xrow = X + (size_t)(row0 + lr) * 128 + lg * 8;
    bf16x8 a[4];
#pragma unroll
    for (int kk = 0; kk < 4; ++kk) {
        const float4 x0 = *(const float4*)(xrow + kk * 32);
        const float4 x1 = *(const float4*)(xrow + kk * 32 + 4);
        bf16x8 av;
        av[0] = bf16r(x0.x); av[1] = bf16r(x0.y);
        av[2] = bf16r(x0.z); av[3] = bf16r(x0.w);
        av[4] = bf16r(x1.x); av[5] = bf16r(x1.y);
        av[6] = bf16r(x1.z); av[7] = bf16r(x1.w);
        a[kk] = av;
    }

#pragma unroll
    for (int nt = 0; nt < 4; ++nt) {
        const int col = col0 + nt * 16 + lr;
        const short* wrow = Wz + col * 128 + lg * 8;
        f32x4 acc = {0.f, 0.f, 0.f, 0.f};
#pragma unroll
        for (int kk = 0; kk < 4; ++kk) {
            const bf16x8 b = *(const bf16x8*)(wrow + kk * 32);
            acc = __builtin_amdgcn_mfma_f32_16x16x32_bf16(a[kk], b, acc, 0, 0, 0);
        }
        const float bc = bias[col];
#pragma unroll
        for (int j = 0; j < 4; ++j) {
            Y[(size_t)(row0 + lg * 4 + j) * 128 + col] = (acc[j] + bc) * scale;
        }
    }
}

// ---------------------------------------------------------------------------
// fp32 GEMM body (R2 version, known-good): 16 rows/block, 512 blocks.
// Kept fp32 for the final projection to protect the error budget.
// ---------------------------------------------------------------------------
__global__ __launch_bounds__(256) void out_gemm(
    const float* __restrict__ X, const float* __restrict__ W,
    const float* __restrict__ bias, float* __restrict__ Y)
{
    __shared__ float4 Xs[16 * 32];  // 16 rows x 128 floats

    const int t = threadIdx.x;
    const float4* Xg = (const float4*)(X + (size_t)blockIdx.x * 16 * 128);
    Xs[t]       = Xg[t];
    Xs[t + 256] = Xg[t + 256];
    __syncthreads();

    const int col = t & 127;
    const int rg  = t >> 7;  // 0 or 1
    const float4* xs = Xs + rg * 8 * 32;

    float acc[8];
    const float bc = bias[col];
#pragma unroll
    for (int r = 0; r < 8; ++r) acc[r] = bc;

#pragma unroll 4
    for (int k4 = 0; k4 < 32; ++k4) {
        const float w0 = W[(4 * k4 + 0) * 128 + col];
        const float w1 = W[(4 * k4 + 1) * 128 + col];
        const float w2 = W[(4 * k4 + 2) * 128 + col];
        const float w3 = W[(4 * k4 + 3) * 128 + col];
#pragma unroll
        for (int r = 0; r < 8; ++r) {
            float4 x = xs[r * 32 + k4];
            acc[r] = fmaf(x.x, w0, acc[r]);
            acc[r] = fmaf(x.y, w1, acc[r]);
            acc[r] = fmaf(x.z, w2, acc[r]);
            acc[r] = fmaf(x.w, w3, acc[r]);
        }
    }

    float* Yg = Y + (size_t)blockIdx.x * 16 * 128;
#pragma unroll
    for (int r = 0; r < 8; ++r) Yg[(rg * 8 + r) * 128 + col] = acc[r];
}

// ---------------------------------------------------------------------------
// NATTEN edge-index helper (L=64, K=7, dil=2, ns=3).
// ---------------------------------------------------------------------------
__device__ __forceinline__ void natten_idx(int i, int& s, int& p)
{
    if (i < 6) {                 // i - ns*dil < 0
        s = i & 1;
        p = 6 - (i >> 1);
    } else if (i >= 58) {        // i + ns*dil >= L  (L%dil==0 -> b=0 path)
        s = 50 + (i & 1);        // a + i%dil - K*dil
        p = (63 - i) >> 1;
    } else {
        s = i - 6;
        p = 3;
    }
}

// ---------------------------------------------------------------------------
// Neighborhood attention, two-pass register version (R3, measured ~15 us).
// 8 lanes per (b,i,j,head); each lane owns 4 channels.
// ---------------------------------------------------------------------------
__global__ __launch_bounds__(256) void natten_kernel(
    const float* __restrict__ qh, const float* __restrict__ kh,
    const float* __restrict__ vh, const float* __restrict__ rpb,
    float* __restrict__ att)
{
    const int glob = blockIdx.x * 256 + threadIdx.x;  // 0..262143
    const int q4 = glob & 7;          // channel quarter (4 floats)
    const int n  = (glob >> 3) & 3;   // head
    const int j  = (glob >> 5) & 63;
    const int i  = (glob >> 11) & 63;
    const int b  = glob >> 17;

    int si, pi0, sj, pj0;
    natten_idx(i, si, pi0);
    natten_idx(j, sj, pj0);

    const int coff = n * 32 + q4 * 4;
    const size_t pix = (size_t)(b * 4096 + i * 64 + j);
    const float4 qv = *(const float4*)(qh + pix * 128 + coff);

    const float* rp = rpb + n * 169;  // [13][13]

    float sc[49];

    // ---- Pass 1: partial dot products (independent loads, no chain) ----
#pragma unroll
    for (int ki = 0; ki < 7; ++ki) {
        const int iy = si + 2 * ki;
        const size_t rowbase = ((size_t)(b * 4096 + iy * 64)) * 128 + coff;
#pragma unroll
        for (int kj = 0; kj < 7; ++kj) {
            const int ix = sj + 2 * kj;
            const float4 kv = *(const float4*)(kh + rowbase + (size_t)ix * 128);
            sc[ki * 7 + kj] =
                fmaf(qv.x, kv.x, fmaf(qv.y, kv.y, fmaf(qv.z, kv.z, qv.w * kv.w)));
        }
    }

    // ---- Cross-lane reduce: 3 rounds of independent shuffles ----
#pragma unroll
    for (int t = 0; t < 49; ++t) sc[t] += __shfl_xor(sc[t], 1);
#pragma unroll
    for (int t = 0; t < 49; ++t) sc[t] += __shfl_xor(sc[t], 2);
#pragma unroll
    for (int t = 0; t < 49; ++t) sc[t] += __shfl_xor(sc[t], 4);

    // ---- Bias + max (4 partial maxes) ----
    float m0 = -1e30f, m1 = -1e30f, m2 = -1e30f, m3 = -1e30f;
#pragma unroll
    for (int t = 0; t < 49; ++t) {
        const int ki = t / 7, kj = t % 7;
        sc[t] += rp[(pi0 + ki) * 13 + (pj0 + kj)];
        if ((t & 3) == 0)      m0 = fmaxf(m0, sc[t]);
        else if ((t & 3) == 1) m1 = fmaxf(m1, sc[t]);
        else if ((t & 3) == 2) m2 = fmaxf(m2, sc[t]);
        else                   m3 = fmaxf(m3, sc[t]);
    }
    const float m = fmaxf(fmaxf(m0, m1), fmaxf(m2, m3));

    // ---- Exponentials (independent) + 4-way partial sums ----
    float l0 = 0.f, l1 = 0.f, l2 = 0.f, l3 = 0.f;
#pragma unroll
    for (int t = 0; t < 49; ++t) {
        const float p = __expf(sc[t] - m);
        sc[t] = p;
        if ((t & 3) == 0)      l0 += p;
        else if ((t & 3) == 1) l1 += p;
        else if ((t & 3) == 2) l2 += p;
        else                   l3 += p;
    }
    const float inv = 1.0f / ((l0 + l1) + (l2 + l3));

    // ---- Pass 2: PV accumulation (2 chains per channel) ----
    float4 oa = make_float4(0.f, 0.f, 0.f, 0.f);
    float4 ob = make_float4(0.f, 0.f, 0.f, 0.f);
#pragma unroll
    for (int ki = 0; ki < 7; ++ki) {
        const int iy = si + 2 * ki;
        const size_t rowbase = ((size_t)(b * 4096 + iy * 64)) * 128 + coff;
#pragma unroll
        for (int kj = 0; kj < 7; ++kj) {
            const int ix = sj + 2 * kj;
            const float4 vv = *(const float4*)(vh + rowbase + (size_t)ix * 128);
            const float p = sc[ki * 7 + kj];
            if (((ki * 7 + kj) & 1) == 0) {
                oa.x = fmaf(p, vv.x, oa.x);
                oa.y = fmaf(p, vv.y, oa.y);
                oa.z = fmaf(p, vv.z, oa.z);
                oa.w = fmaf(p, vv.w, oa.w);
            } else {
                ob.x = fmaf(p, vv.x, ob.x);
                ob.y = fmaf(p, vv.y, ob.y);
                ob.z = fmaf(p, vv.z, ob.z);
                ob.w = fmaf(p, vv.w, ob.w);
            }
        }
    }

    float4* op = (float4*)(att + pix * 128 + coff);
    *op = make_float4((oa.x + ob.x) * inv, (oa.y + ob.y) * inv,
                      (oa.z + ob.z) * inv, (oa.w + ob.w) * inv);
}

// ---------------------------------------------------------------------------
extern "C" void kernel_launch(void* const* d_in, const int* in_sizes, int n_in,
                              void* d_out, int out_size, void* d_ws, size_t ws_size,
                              hipStream_t stream)
{
    const float* q   = (const float*)d_in[0];
    const float* k   = (const float*)d_in[1];
    const float* v   = (const float*)d_in[2];
    const float* Wq  = (const float*)d_in[3];
    const float* bq  = (const float*)d_in[4];
    const float* Wk  = (const float*)d_in[5];
    const float* bk  = (const float*)d_in[6];
    const float* Wv  = (const float*)d_in[7];
    const float* bv  = (const float*)d_in[8];
    const float* rpb = (const float*)d_in[9];
    const float* Wo  = (const float*)d_in[10];
    const float* bo  = (const float*)d_in[11];

    float* ws  = (float*)d_ws;
    float* qh  = ws;                       // 8192*128 f32
    float* kh  = ws + (size_t)NPIX * 128;
    float* vh  = ws + (size_t)NPIX * 128 * 2;
    float* att = ws + (size_t)NPIX * 128 * 3;
    short* Wt  = (short*)(ws + (size_t)NPIX * 128 * 4);  // [3][128][128] bf16
    float* out = (float*)d_out;

    hipLaunchKernelGGL(prep_w, dim3(3), dim3(256), 0, stream, Wq, Wk, Wv, Wt);

    hipLaunchKernelGGL(qkv_mfma, dim3(256, 3), dim3(256), 0, stream,
                       q, k, v, Wt, bq, bk, bv, qh, kh, vh);

    hipLaunchKernelGGL(natten_kernel, dim3(1024), dim3(256), 0, stream,
                       qh, kh, vh, rpb, att);

    hipLaunchKernelGGL(out_gemm, dim3(512), dim3(256), 0, stream,
                       att, Wo, bo, out);
}

// Round 5
// 46.655 us; speedup vs baseline: 1.8959x; 1.1583x over previous
//
#include <hip/hip_runtime.h>
#include <hip/hip_bf16.h>
#include <math.h>

// Problem constants
#define BB 2
#define HH 64
#define WW 64
#define DIMC 128
#define NH 4
#define HD 32
#define KS 7
#define DIL 2
#define NPIX (BB * HH * WW)         // 8192 rows
#define SCALE 0.17677669529663687f  // 32^-0.5

typedef short bf16x8 __attribute__((ext_vector_type(8)));
typedef float f32x4  __attribute__((ext_vector_type(4)));

__device__ __forceinline__ short bf16r(float f) {
    union { float f; unsigned u; } x; x.f = f;
    unsigned r = x.u + 0x7FFF + ((x.u >> 16) & 1);  // RNE
    return (short)(r >> 16);
}
__device__ __forceinline__ float uasf(unsigned u) {
    union { unsigned u; float f; } x; x.u = u; return x.f;
}

// ---------------------------------------------------------------------------
// prep_w: W f32 [128][128] (row=k,col=n) -> Wt bf16 [z][n][k] (transposed).
// 16 blocks: z = blk>>2 (Wq,Wk,Wv,Wo), ks = blk&3 (32-row k-slice).
// 4 upfront float4 loads per thread -> single HBM latency batch.
// ---------------------------------------------------------------------------
__global__ __launch_bounds__(256) void prep_w(
    const float* __restrict__ Wq, const float* __restrict__ Wk,
    const float* __restrict__ Wv, const float* __restrict__ Wo,
    short* __restrict__ Wt)
{
    const int z  = blockIdx.x >> 2;
    const int ks = blockIdx.x & 3;
    const float* W = (z == 0) ? Wq : (z == 1) ? Wk : (z == 2) ? Wv : Wo;

    __shared__ short T[32][136];   // [r][c], 272B rows (8B-aligned short4 writes)
    const int t = threadIdx.x;
    const float4* Wg = (const float4*)(W + ks * 32 * 128);

    float4 xv[4];
#pragma unroll
    for (int u = 0; u < 4; ++u) xv[u] = Wg[u * 256 + t];
#pragma unroll
    for (int u = 0; u < 4; ++u) {
        const int e = u * 256 + t;
        const int r = e >> 5;
        const int c = (e & 31) * 4;
        short4 s4;
        s4.x = bf16r(xv[u].x); s4.y = bf16r(xv[u].y);
        s4.z = bf16r(xv[u].z); s4.w = bf16r(xv[u].w);
        *(short4*)&T[r][c] = s4;
    }
    __syncthreads();

    const int c = t >> 1;
    const int h = (t & 1) * 16;
    bf16x8 lo, hi;
#pragma unroll
    for (int i = 0; i < 8; ++i) { lo[i] = T[h + i][c]; hi[i] = T[h + 8 + i][c]; }
    short* outp = Wt + z * 16384 + c * 128 + ks * 32 + h;
    *(bf16x8*)(outp)     = lo;
    *(bf16x8*)(outp + 8) = hi;
}

// ---------------------------------------------------------------------------
// qkv_mfma: Y = (X @ W + b) * scale via v_mfma_f32_16x16x32_bf16.
// Block = 32 rows, 4 waves; wave = 16 rows x 64 cols. All 16 B-frags preloaded
// (16 outstanding b128 loads). z=0 -> qh f32; z=1,2 -> kh/vh bf16.
// Layouts (R4-verified): A/B lane: row/col=lane&15, k=kk*32+(lane>>4)*8+e;
// C/D: col=lane&15, row=(lane>>4)*4+j.
// ---------------------------------------------------------------------------
__global__ __launch_bounds__(256) void qkv_mfma(
    const float* __restrict__ q, const float* __restrict__ k,
    const float* __restrict__ v, const short* __restrict__ Wt,
    const float* __restrict__ bq, const float* __restrict__ bk,
    const float* __restrict__ bv,
    float* __restrict__ qh, short* __restrict__ khb, short* __restrict__ vhb)
{
    const int z = blockIdx.y;
    const float* X    = (z == 0) ? q  : (z == 1) ? k  : v;
    const float* bias = (z == 0) ? bq : (z == 1) ? bk : bv;
    const short* Wz   = Wt + z * 16384;

    const int t    = threadIdx.x;
    const int wv   = t >> 6;
    const int lane = t & 63;
    const int lr   = lane & 15;
    const int lg   = lane >> 4;
    const int row0 = blockIdx.x * 32 + (wv & 1) * 16;
    const int col0 = (wv >> 1) * 64;

    // Preload all B fragments (16 b128 loads in flight)
    bf16x8 bfr[16];
#pragma unroll
    for (int nt = 0; nt < 4; ++nt) {
        const short* wrow = Wz + (col0 + nt * 16 + lr) * 128 + lg * 8;
#pragma unroll
        for (int kk = 0; kk < 4; ++kk)
            bfr[nt * 4 + kk] = *(const bf16x8*)(wrow + kk * 32);
    }

    // A fragments: f32 loads + bf16 pack
    const float* xrow = X + (size_t)(row0 + lr) * 128 + lg * 8;
    bf16x8 a[4];
#pragma unroll
    for (int kk = 0; kk < 4; ++kk) {
        const float4 x0 = *(const float4*)(xrow + kk * 32);
        const float4 x1 = *(const float4*)(xrow + kk * 32 + 4);
        bf16x8 av;
        av[0] = bf16r(x0.x); av[1] = bf16r(x0.y);
        av[2] = bf16r(x0.z); av[3] = bf16r(x0.w);
        av[4] = bf16r(x1.x); av[5] = bf16r(x1.y);
        av[6] = bf16r(x1.z); av[7] = bf16r(x1.w);
        a[kk] = av;
    }

#pragma unroll
    for (int nt = 0; nt < 4; ++nt) {
        const int col = col0 + nt * 16 + lr;
        f32x4 acc = {0.f, 0.f, 0.f, 0.f};
#pragma unroll
        for (int kk = 0; kk < 4; ++kk)
            acc = __builtin_amdgcn_mfma_f32_16x16x32_bf16(a[kk], bfr[nt * 4 + kk], acc, 0, 0, 0);
        const float bc = bias[col];
        if (z == 0) {
#pragma unroll
            for (int j = 0; j < 4; ++j)
                qh[(size_t)(row0 + lg * 4 + j) * 128 + col] = (acc[j] + bc) * SCALE;
        } else {
            short* Yb = (z == 1) ? khb : vhb;
#pragma unroll
            for (int j = 0; j < 4; ++j)
                Yb[(size_t)(row0 + lg * 4 + j) * 128 + col] = bf16r(acc[j] + bc);
        }
    }
}

// ---------------------------------------------------------------------------
// out_mfma: out = att(bf16) @ Wo + bo, f32 output. Same wave structure.
// ---------------------------------------------------------------------------
__global__ __launch_bounds__(256) void out_mfma(
    const short* __restrict__ attb, const short* __restrict__ Wt,
    const float* __restrict__ bo, float* __restrict__ out)
{
    const short* Wz = Wt + 3 * 16384;

    const int t    = threadIdx.x;
    const int wv   = t >> 6;
    const int lane = t & 63;
    const int lr   = lane & 15;
    const int lg   = lane >> 4;
    const int row0 = blockIdx.x * 32 + (wv & 1) * 16;
    const int col0 = (wv >> 1) * 64;

    bf16x8 bfr[16];
#pragma unroll
    for (int nt = 0; nt < 4; ++nt) {
        const short* wrow = Wz + (col0 + nt * 16 + lr) * 128 + lg * 8;
#pragma unroll
        for (int kk = 0; kk < 4; ++kk)
            bfr[nt * 4 + kk] = *(const bf16x8*)(wrow + kk * 32);
    }

    const short* xrow = attb + (size_t)(row0 + lr) * 128 + lg * 8;
    bf16x8 a[4];
#pragma unroll
    for (int kk = 0; kk < 4; ++kk) a[kk] = *(const bf16x8*)(xrow + kk * 32);

#pragma unroll
    for (int nt = 0; nt < 4; ++nt) {
        const int col = col0 + nt * 16 + lr;
        f32x4 acc = {0.f, 0.f, 0.f, 0.f};
#pragma unroll
        for (int kk = 0; kk < 4; ++kk)
            acc = __builtin_amdgcn_mfma_f32_16x16x32_bf16(a[kk], bfr[nt * 4 + kk], acc, 0, 0, 0);
        const float bc = bo[col];
#pragma unroll
        for (int j = 0; j < 4; ++j)
            out[(size_t)(row0 + lg * 4 + j) * 128 + col] = acc[j] + bc;
    }
}

// ---------------------------------------------------------------------------
// NATTEN edge-index helper (L=64, K=7, dil=2, ns=3).
// ---------------------------------------------------------------------------
__device__ __forceinline__ void natten_idx(int i, int& s, int& p)
{
    if (i < 6) {                 // i - ns*dil < 0
        s = i & 1;
        p = 6 - (i >> 1);
    } else if (i >= 58) {        // i + ns*dil >= L  (L%dil==0 -> b=0 path)
        s = 50 + (i & 1);        // a + i%dil - K*dil
        p = (63 - i) >> 1;
    } else {
        s = i - 6;
        p = 3;
    }
}

// ---------------------------------------------------------------------------
// Neighborhood attention, two-pass register version; K/V bf16, att bf16 out.
// 8 lanes per (b,i,j,head); each lane owns 4 channels. q stays f32.
// ---------------------------------------------------------------------------
__global__ __launch_bounds__(256) void natten_kernel(
    const float* __restrict__ qh, const short* __restrict__ khb,
    const short* __restrict__ vhb, const float* __restrict__ rpb,
    short* __restrict__ attb)
{
    const int glob = blockIdx.x * 256 + threadIdx.x;  // 0..262143
    const int q4 = glob & 7;          // channel quarter (4 elems)
    const int n  = (glob >> 3) & 3;   // head
    const int j  = (glob >> 5) & 63;
    const int i  = (glob >> 11) & 63;
    const int b  = glob >> 17;

    int si, pi0, sj, pj0;
    natten_idx(i, si, pi0);
    natten_idx(j, sj, pj0);

    const int coff = n * 32 + q4 * 4;
    const size_t pix = (size_t)(b * 4096 + i * 64 + j);
    const float4 qv = *(const float4*)(qh + pix * 128 + coff);

    const float* rp = rpb + n * 169;  // [13][13]

    float sc[49];

    // ---- Pass 1: partial dot products (bf16 K, bit-shift converts) ----
#pragma unroll
    for (int ki = 0; ki < 7; ++ki) {
        const int iy = si + 2 * ki;
        const size_t rowbase = ((size_t)(b * 4096 + iy * 64)) * 128 + coff;
#pragma unroll
        for (int kj = 0; kj < 7; ++kj) {
            const int ix = sj + 2 * kj;
            const uint2 kv = *(const uint2*)(khb + rowbase + (size_t)ix * 128);
            const float k0 = uasf(kv.x << 16);
            const float k1 = uasf(kv.x & 0xFFFF0000u);
            const float k2 = uasf(kv.y << 16);
            const float k3 = uasf(kv.y & 0xFFFF0000u);
            sc[ki * 7 + kj] =
                fmaf(qv.x, k0, fmaf(qv.y, k1, fmaf(qv.z, k2, qv.w * k3)));
        }
    }

    // ---- Cross-lane reduce: 3 rounds of independent shuffles ----
#pragma unroll
    for (int t = 0; t < 49; ++t) sc[t] += __shfl_xor(sc[t], 1);
#pragma unroll
    for (int t = 0; t < 49; ++t) sc[t] += __shfl_xor(sc[t], 2);
#pragma unroll
    for (int t = 0; t < 49; ++t) sc[t] += __shfl_xor(sc[t], 4);

    // ---- Bias + max (4 partial maxes) ----
    float m0 = -1e30f, m1 = -1e30f, m2 = -1e30f, m3 = -1e30f;
#pragma unroll
    for (int t = 0; t < 49; ++t) {
        const int ki = t / 7, kj = t % 7;
        sc[t] += rp[(pi0 + ki) * 13 + (pj0 + kj)];
        if ((t & 3) == 0)      m0 = fmaxf(m0, sc[t]);
        else if ((t & 3) == 1) m1 = fmaxf(m1, sc[t]);
        else if ((t & 3) == 2) m2 = fmaxf(m2, sc[t]);
        else                   m3 = fmaxf(m3, sc[t]);
    }
    const float m = fmaxf(fmaxf(m0, m1), fmaxf(m2, m3));

    // ---- Exponentials + 4-way partial sums ----
    float l0 = 0.f, l1 = 0.f, l2 = 0.f, l3 = 0.f;
#pragma unroll
    for (int t = 0; t < 49; ++t) {
        const float p = __expf(sc[t] - m);
        sc[t] = p;
        if ((t & 3) == 0)      l0 += p;
        else if ((t & 3) == 1) l1 += p;
        else if ((t & 3) == 2) l2 += p;
        else                   l3 += p;
    }
    const float inv = 1.0f / ((l0 + l1) + (l2 + l3));

    // ---- Pass 2: PV accumulation (bf16 V), 2 chains ----
    float4 oa = make_float4(0.f, 0.f, 0.f, 0.f);
    float4 ob = make_float4(0.f, 0.f, 0.f, 0.f);
#pragma unroll
    for (int ki = 0; ki < 7; ++ki) {
        const int iy = si + 2 * ki;
        const size_t rowbase = ((size_t)(b * 4096 + iy * 64)) * 128 + coff;
#pragma unroll
        for (int kj = 0; kj < 7; ++kj) {
            const int ix = sj + 2 * kj;
            const uint2 vv = *(const uint2*)(vhb + rowbase + (size_t)ix * 128);
            const float v0 = uasf(vv.x << 16);
            const float v1 = uasf(vv.x & 0xFFFF0000u);
            const float v2 = uasf(vv.y << 16);
            const float v3 = uasf(vv.y & 0xFFFF0000u);
            const float p = sc[ki * 7 + kj];
            if (((ki * 7 + kj) & 1) == 0) {
                oa.x = fmaf(p, v0, oa.x);
                oa.y = fmaf(p, v1, oa.y);
                oa.z = fmaf(p, v2, oa.z);
                oa.w = fmaf(p, v3, oa.w);
            } else {
                ob.x = fmaf(p, v0, ob.x);
                ob.y = fmaf(p, v1, ob.y);
                ob.z = fmaf(p, v2, ob.z);
                ob.w = fmaf(p, v3, ob.w);
            }
        }
    }

    ushort4 ow;
    ow.x = (unsigned short)bf16r((oa.x + ob.x) * inv);
    ow.y = (unsigned short)bf16r((oa.y + ob.y) * inv);
    ow.z = (unsigned short)bf16r((oa.z + ob.z) * inv);
    ow.w = (unsigned short)bf16r((oa.w + ob.w) * inv);
    *(ushort4*)(attb + pix * 128 + coff) = ow;
}

// ---------------------------------------------------------------------------
extern "C" void kernel_launch(void* const* d_in, const int* in_sizes, int n_in,
                              void* d_out, int out_size, void* d_ws, size_t ws_size,
                              hipStream_t stream)
{
    const float* q   = (const float*)d_in[0];
    const float* k   = (const float*)d_in[1];
    const float* v   = (const float*)d_in[2];
    const float* Wq  = (const float*)d_in[3];
    const float* bq  = (const float*)d_in[4];
    const float* Wk  = (const float*)d_in[5];
    const float* bk  = (const float*)d_in[6];
    const float* Wv  = (const float*)d_in[7];
    const float* bv  = (const float*)d_in[8];
    const float* rpb = (const float*)d_in[9];
    const float* Wo  = (const float*)d_in[10];
    const float* bo  = (const float*)d_in[11];

    float* ws   = (float*)d_ws;
    float* qh   = ws;                                   // f32 [8192][128]
    short* khb  = (short*)(ws + (size_t)NPIX * 128);    // bf16 [8192][128]
    short* vhb  = khb + (size_t)NPIX * 128;
    short* attb = vhb + (size_t)NPIX * 128;
    short* Wt   = attb + (size_t)NPIX * 128;            // bf16 [4][128][128]
    float* out  = (float*)d_out;

    hipLaunchKernelGGL(prep_w, dim3(16), dim3(256), 0, stream, Wq, Wk, Wv, Wo, Wt);

    hipLaunchKernelGGL(qkv_mfma, dim3(256, 3), dim3(256), 0, stream,
                       q, k, v, Wt, bq, bk, bv, qh, khb, vhb);

    hipLaunchKernelGGL(natten_kernel, dim3(1024), dim3(256), 0, stream,
                       qh, khb, vhb, rpb, attb);

    hipLaunchKernelGGL(out_mfma, dim3(256), dim3(256), 0, stream,
                       attb, Wt, bo, out);
}